// Round 1
// baseline (3797.226 us; speedup 1.0000x reference)
//
#include <hip/hip_runtime.h>
#include <hip/hip_bf16.h>

#define GV 1024
#define BATCH 128
#define M_TOT (BATCH * GV)   // 131072 rows
#define CHEB_K 5

typedef __bf16 bf16x8 __attribute__((ext_vector_type(8)));
typedef float  f32x4  __attribute__((ext_vector_type(4)));

// ---------------------------------------------------------------------------
// W [N, Ci*5] fp32 (f = c*5+k, torch order)  ->  Wb [N, KdPad] bf16 (f' = k*Ci+c)
__global__ void k_convw(const float* __restrict__ W, __hip_bfloat16* __restrict__ Wb,
                        int Ci, int N, int KdPad) {
    int idx = blockIdx.x * 256 + threadIdx.x;
    if (idx >= N * KdPad) return;
    int o = idx / KdPad, f = idx % KdPad;
    float v = 0.f;
    if (f < CHEB_K * Ci) {
        int k = f / Ci, c = f % Ci;
        v = W[(size_t)o * CHEB_K * Ci + c * CHEB_K + k];
    }
    Wb[idx] = __float2bfloat16(v);
}

// ---------------------------------------------------------------------------
__device__ __forceinline__ void store_bf4(__hip_bfloat16* p, f32x4 v) {
    union { __hip_bfloat16 h[4]; uint2 u; } t;
    #pragma unroll
    for (int c = 0; c < 4; ++c) t.h[c] = __float2bfloat16(v[c]);
    *(uint2*)p = t.u;   // 8B-aligned by construction (see call sites)
}

// ---------------------------------------------------------------------------
// Layer 0 Chebyshev expansion: Ci=3, KdPad=32, input layout [B, 3, V].
// Small (Bc blocks); 36 KB LDS -> 4 blocks/CU. Zero-pad cols 15..31 folded in.
__global__ __launch_bounds__(512, 4)
void k_cheb0(const float* __restrict__ X, __hip_bfloat16* __restrict__ F, int bOff) {
    __shared__ float T[3][3072];
    int tid = threadIdx.x;
    int b = blockIdx.x + bOff;
    size_t fBase = ((size_t)blockIdx.x) << 10;
    for (int i = tid; i < 3072; i += 512) {
        int u = i / 3, c = i - (i / 3) * 3;
        float v = X[((size_t)b * 3 + c) * GV + u];
        F[(fBase + u) * 32 + c] = __float2bfloat16(v);
        int gi = u >> 5, gj = u & 31;
        int deg = (gi > 0) + (gi < 31) + (gj > 0) + (gj < 31);
        T[0][i] = v * rsqrtf((float)deg);
    }
    for (int i = tid; i < 1024 * 17; i += 512) {
        int u = i / 17, f = i - (i / 17) * 17;
        F[(fBase + u) * 32 + 15 + f] = __float2bfloat16(0.f);
    }
    __syncthreads();
    for (int k = 1; k < CHEB_K; ++k) {
        const float* src = T[(k - 1) % 3];
        const float* old = T[(k + 1) % 3];
        float* dst = T[k % 3];
        for (int i = tid; i < 3072; i += 512) {
            int u = i / 3, c = i - (i / 3) * 3;
            int gi = u >> 5, gj = u & 31;
            float s = 0.f;
            if (gi > 0)  s += src[i - 96];
            if (gi < 31) s += src[i + 96];
            if (gj > 0)  s += src[i - 3];
            if (gj < 31) s += src[i + 3];
            int deg = (gi > 0) + (gi < 31) + (gj > 0) + (gj < 31);
            float invdeg = (deg == 4) ? 0.25f : (deg == 3 ? (1.f / 3.f) : 0.5f);
            float val = (k == 1) ? (-s * invdeg) : (-2.f * invdeg * s - old[i]);
            dst[i] = val;
            F[(fBase + u) * 32 + k * 3 + c] = __float2bfloat16(val * sqrtf((float)deg));
        }
        __syncthreads();
    }
}

// ---------------------------------------------------------------------------
// Layers 1..6 Chebyshev expansion, 4 channels per block, fully vectorized.
// Fused BN+ReLU of the previous layer on load. LDS = 48 KB -> 3 blocks/CU.
// Recursion kept in degree-scaled space S = D^{-1/2} T (stencil weight 1/deg):
//   S_1 = -invdeg * sum_N S_0,  S_k = -2*invdeg*sum_N S_{k-1} - S_{k-2}
//   T_k = sqrt(deg) * S_k.
__global__ __launch_bounds__(512, 6)
void k_cheb4(const float* __restrict__ X, const float* __restrict__ stats,
             const float* __restrict__ g, const float* __restrict__ bb,
             __hip_bfloat16* __restrict__ F, int Cin, int KdPad, int bOff) {
    __shared__ f32x4 T[3][1024];    // 48 KB
    int tid = threadIdx.x;
    int b = blockIdx.y + bOff;
    int c0 = blockIdx.x * 4;
    const float invM = 1.0f / (float)M_TOT;
    size_t mBase = ((size_t)b) << 10;
    size_t fBase = ((size_t)blockIdx.y) << 10;   // F rows are chunk-local

    float mean[4], isd[4], bias[4];
    #pragma unroll
    for (int c = 0; c < 4; ++c) {
        int cg = c0 + c;
        float m = stats[cg] * invM;
        float v = stats[Cin + cg] * invM - m * m;
        mean[c] = m;
        isd[c]  = rsqrtf(v + 1e-5f) * g[cg];
        bias[c] = bb[cg];
    }

    // ---- load T0 with fused BN+ReLU ----
    #pragma unroll
    for (int t = 0; t < 2; ++t) {
        int u = tid + t * 512;
        f32x4 v = *(const f32x4*)(X + (mBase + u) * Cin + c0);
        #pragma unroll
        for (int c = 0; c < 4; ++c) {
            float x = (v[c] - mean[c]) * isd[c] + bias[c];
            v[c] = x > 0.f ? x : 0.f;
        }
        store_bf4(F + (fBase + u) * KdPad + c0, v);
        int gi = u >> 5, gj = u & 31;
        int deg = (gi > 0) + (gi < 31) + (gj > 0) + (gj < 31);
        T[0][u] = v * rsqrtf((float)deg);
    }
    __syncthreads();

    // ---- recursion k = 1..4 ----
    for (int k = 1; k < CHEB_K; ++k) {
        const f32x4* src = T[(k - 1) % 3];
        const f32x4* old = T[(k + 1) % 3];     // == (k-2) mod 3
        f32x4* dst = T[k % 3];
        #pragma unroll
        for (int t = 0; t < 2; ++t) {
            int u = tid + t * 512;
            int gi = u >> 5, gj = u & 31;
            f32x4 s = (f32x4){0.f, 0.f, 0.f, 0.f};
            if (gi > 0)  s += src[u - 32];
            if (gi < 31) s += src[u + 32];
            if (gj > 0)  s += src[u - 1];
            if (gj < 31) s += src[u + 1];
            int deg = (gi > 0) + (gi < 31) + (gj > 0) + (gj < 31);
            float invdeg = (deg == 4) ? 0.25f : (deg == 3 ? (1.f / 3.f) : 0.5f);
            f32x4 val = (k == 1) ? s * (-invdeg) : s * (-2.f * invdeg) - old[u];
            dst[u] = val;
            store_bf4(F + (fBase + u) * KdPad + k * Cin + c0, val * sqrtf((float)deg));
        }
        __syncthreads();
    }
}

// ---------------------------------------------------------------------------
// bf16 MFMA GEMM: Y[M_loc, N] = F[M_loc, KdPad] @ Wb[N, KdPad]^T   (fp32 out)
// + fused per-channel sum/sumsq accumulation into stats (for next-layer BN).
// Block = 256 thr = 4 waves; wave owns 32 rows (2 m-tiles), all N columns.
// Fragments loaded straight from global (A: HBM stream, B: L2-resident).
template<int NT>
__global__ __launch_bounds__(256, 2)
void k_gemm_bf16(const __hip_bfloat16* __restrict__ A, const __hip_bfloat16* __restrict__ Bw,
                 float* __restrict__ Y, float* __restrict__ stats, int KdPad) {
    constexpr int N = NT * 16;
    __shared__ float ls[2 * N];
    int tid = threadIdx.x;
    for (int t = tid; t < 2 * N; t += 256) ls[t] = 0.f;
    __syncthreads();
    int lane = tid & 63, wv = tid >> 6;
    int col = lane & 15, quad = lane >> 4;
    size_t m0 = (size_t)blockIdx.x * 128 + wv * 32;
    f32x4 acc[2][NT];
    #pragma unroll
    for (int t = 0; t < 2; ++t)
        #pragma unroll
        for (int n = 0; n < NT; ++n) acc[t][n] = (f32x4){0.f, 0.f, 0.f, 0.f};
    const __hip_bfloat16* Ap0 = A + (m0 + col) * (size_t)KdPad + quad * 8;
    const __hip_bfloat16* Ap1 = Ap0 + 16 * (size_t)KdPad;
    const __hip_bfloat16* Bp  = Bw + (size_t)col * KdPad + quad * 8;
    for (int k0 = 0; k0 < KdPad; k0 += 32) {
        bf16x8 a0 = *(const bf16x8*)(Ap0 + k0);
        bf16x8 a1 = *(const bf16x8*)(Ap1 + k0);
        #pragma unroll
        for (int n = 0; n < NT; ++n) {
            bf16x8 bf = *(const bf16x8*)(Bp + (size_t)(n * 16) * KdPad + k0);
            acc[0][n] = __builtin_amdgcn_mfma_f32_16x16x32_bf16(a0, bf, acc[0][n], 0, 0, 0);
            acc[1][n] = __builtin_amdgcn_mfma_f32_16x16x32_bf16(a1, bf, acc[1][n], 0, 0, 0);
        }
    }
    // epilogue: store Y + per-channel partial stats
    #pragma unroll
    for (int t = 0; t < 2; ++t) {
        #pragma unroll
        for (int n = 0; n < NT; ++n) {
            size_t r0 = m0 + t * 16 + quad * 4;
            int cg = n * 16 + col;
            float s = 0.f, s2 = 0.f;
            #pragma unroll
            for (int r = 0; r < 4; ++r) {
                float v = acc[t][n][r];
                Y[(r0 + r) * N + cg] = v;
                s += v; s2 += v * v;
            }
            s  += __shfl_xor(s, 16, 64);  s  += __shfl_xor(s, 32, 64);
            s2 += __shfl_xor(s2, 16, 64); s2 += __shfl_xor(s2, 32, 64);
            if (quad == 0) { atomicAdd(&ls[cg], s); atomicAdd(&ls[N + cg], s2); }
        }
    }
    __syncthreads();
    for (int t = tid; t < 2 * N; t += 256) atomicAdd(&stats[t], ls[t]);
}

// ---------------------------------------------------------------------------
// final BN+ReLU fused with transpose: h [M,96] -> ht [B,96,V]
__global__ void k_bn_transpose_h(const float* __restrict__ h, const float* __restrict__ stats,
                                 const float* __restrict__ g, const float* __restrict__ bb,
                                 float* __restrict__ ht) {
    int idx = blockIdx.x * 256 + threadIdx.x;
    if (idx >= BATCH * 96 * GV) return;
    int v = idx & (GV - 1);
    int c = (idx / GV) % 96;
    int b = idx / (96 * GV);
    const float invM = 1.0f / (float)M_TOT;
    float mean = stats[c] * invM;
    float var  = stats[96 + c] * invM - mean * mean;
    float x = (h[((size_t)b * GV + v) * 96 + c] - mean) * rsqrtf(var + 1e-5f) * g[c] + bb[c];
    ht[idx] = x > 0.f ? x : 0.f;
}

// ---------------------------------------------------------------------------
__global__ void k_classifier(const float* __restrict__ ht, const float* __restrict__ w,
                             const float* __restrict__ bias, float* __restrict__ out) {
    int b = blockIdx.x, o = blockIdx.y;
    const float4* hb = (const float4*)(ht + (size_t)b * 96 * GV);
    const float4* wo = (const float4*)(w + (size_t)o * 96 * GV);
    float acc = 0.f;
    for (int f = threadIdx.x; f < 96 * GV / 4; f += 256) {
        float4 a = hb[f], c4 = wo[f];
        acc += a.x * c4.x + a.y * c4.y + a.z * c4.z + a.w * c4.w;
    }
    #pragma unroll
    for (int off = 32; off > 0; off >>= 1) acc += __shfl_down(acc, off, 64);
    __shared__ float red[4];
    int lane = threadIdx.x & 63, wvv = threadIdx.x >> 6;
    if (lane == 0) red[wvv] = acc;
    __syncthreads();
    if (threadIdx.x == 0) out[b * 10 + o] = red[0] + red[1] + red[2] + red[3] + bias[o];
}

// ---------------------------------------------------------------------------
extern "C" void kernel_launch(void* const* d_in, const int* in_sizes, int n_in,
                              void* d_out, int out_size, void* d_ws, size_t ws_size,
                              hipStream_t stream) {
    const float* x = (const float*)d_in[0];
    const float* wts[7]; const float* gs[7]; const float* bs[7];
    for (int i = 0; i < 7; ++i) {
        wts[i] = (const float*)d_in[2 + 3 * i];
        gs[i]  = (const float*)d_in[3 + 3 * i];
        bs[i]  = (const float*)d_in[4 + 3 * i];
    }
    const float* clfw = (const float*)d_in[23];
    const float* clfb = (const float*)d_in[24];
    float* out = (float*)d_out;

    const int fin[7]  = {3, 96, 96, 96, 192, 192, 192};
    const int fout[7] = {96, 96, 96, 192, 192, 192, 96};
    int KdPad[7];
    for (int i = 0; i < 7; ++i) KdPad[i] = (fin[i] == 3) ? 32 : fin[i] * CHEB_K;

    // ---- workspace layout (floats) ----
    const size_t BIG = (size_t)M_TOT * 192;
    float* ws = (float*)d_ws;
    float* bufA = ws;
    float* bufB = ws + BIG;
    float* stats = ws + 2 * BIG;                 // 7 * 384 floats
    __hip_bfloat16* Wb = (__hip_bfloat16*)(stats + 7 * 384);
    size_t wbOff[7], wtot = 0;
    for (int i = 0; i < 7; ++i) { wbOff[i] = wtot; wtot += (size_t)fout[i] * KdPad[i]; }
    wtot = (wtot + 7) & ~(size_t)7;              // keep F 16B-aligned
    __hip_bfloat16* F = Wb + wtot;
    size_t usedBytes = (size_t)((char*)F - (char*)ws);
    size_t availBf16 = (ws_size > usedBytes) ? (ws_size - usedBytes) / 2 : 0;
    size_t Fneed = (size_t)M_TOT * 960;          // bf16 elems at nch=1
    int nch = 1;
    while (nch < 16 && Fneed / nch > availBf16) nch <<= 1;   // deterministic in ws_size

    hipMemsetAsync(stats, 0, 7 * 384 * sizeof(float), stream);
    for (int i = 0; i < 7; ++i) {
        int tot = fout[i] * KdPad[i];
        hipLaunchKernelGGL(k_convw, dim3((tot + 255) / 256), dim3(256), 0, stream,
                           wts[i], Wb + wbOff[i], fin[i], fout[i], KdPad[i]);
    }

    float* cur = nullptr;
    float* nxt = bufA;
    int Bc = BATCH / nch;                        // batches per chunk
    for (int li = 0; li < 7; ++li) {
        int Ci = fin[li], Co = fout[li];
        const float* Xin = (li == 0) ? x : cur;
        for (int ch = 0; ch < nch; ++ch) {
            int bOff = ch * Bc;
            if (li == 0) {
                hipLaunchKernelGGL(k_cheb0, dim3(Bc), dim3(512), 0, stream,
                                   x, F, bOff);
            } else {
                hipLaunchKernelGGL(k_cheb4, dim3(Ci / 4, Bc), dim3(512), 0, stream,
                                   Xin, stats + (li - 1) * 384, gs[li - 1], bs[li - 1],
                                   F, Ci, KdPad[li], bOff);
            }
            float* Yc = nxt + (size_t)bOff * GV * Co;
            dim3 gg(Bc * 8);                      // (Bc*1024)/128 blocks
            if (Co == 96)
                hipLaunchKernelGGL(k_gemm_bf16<6>, gg, dim3(256), 0, stream,
                                   F, Wb + wbOff[li], Yc, stats + li * 384, KdPad[li]);
            else
                hipLaunchKernelGGL(k_gemm_bf16<12>, gg, dim3(256), 0, stream,
                                   F, Wb + wbOff[li], Yc, stats + li * 384, KdPad[li]);
        }
        cur = nxt;
        nxt = (nxt == bufA) ? bufB : bufA;
    }
    // cur = Y6 [M,96]; apply BN+ReLU while transposing to [B,96,V] into nxt
    hipLaunchKernelGGL(k_bn_transpose_h, dim3((BATCH * 96 * GV + 255) / 256), dim3(256), 0, stream,
                       cur, stats + 6 * 384, gs[6], bs[6], nxt);
    hipLaunchKernelGGL(k_classifier, dim3(BATCH, 10), dim3(256), 0, stream, nxt, clfw, clfb, out);
}

// Round 3
// 1553.524 us; speedup vs baseline: 2.4443x; 2.4443x over previous
//
#include <hip/hip_runtime.h>
#include <hip/hip_bf16.h>

#define GV 1024
#define BATCH 128
#define M_TOT (BATCH * GV)   // 131072 rows
#define CHEB_K 5

typedef __bf16 bf16x8 __attribute__((ext_vector_type(8)));
typedef float  f32x4  __attribute__((ext_vector_type(4)));

// Wb offsets (bf16 elems): L0 [96][32]; L1..6 [Co][Ci/32][160] (deg-major K)
// sizes: L0 3072; L1,L2 46080 (96*3*160); L3 92160 (192*3*160);
//        L4,L5 184320 (192*6*160); L6 92160 (96*6*160)
#define WOFF0 0
#define WOFF1 3072
#define WOFF2 49152
#define WOFF3 95232
#define WOFF4 187392
#define WOFF5 371712
#define WOFF6 556032
#define WTOT  648192

// ---------------------------------------------------------------------------
// Repack all 7 layer weights in one dispatch. blockIdx.y = layer.
// L0: Wb[o*32 + f], f = k*3+c (pad 15..31 = 0).
// L1..6: Wb[o*(NCH*160) + ch*160 + d*32 + cl], source c = ch*32+cl, W[o][c*5+d].
__global__ void k_convw_all(const float* __restrict__ w0, const float* __restrict__ w1,
                            const float* __restrict__ w2, const float* __restrict__ w3,
                            const float* __restrict__ w4, const float* __restrict__ w5,
                            const float* __restrict__ w6, __hip_bfloat16* __restrict__ Wb) {
    const int li = blockIdx.y;
    const int CI[7]     = {3, 96, 96, 96, 192, 192, 192};
    const int NCHt[7]   = {0, 3, 3, 3, 6, 6, 6};
    const int SZ[7]     = {3072, 46080, 46080, 92160, 184320, 184320, 92160};
    const size_t OFF[7] = {WOFF0, WOFF1, WOFF2, WOFF3, WOFF4, WOFF5, WOFF6};
    const float* Ws[7]  = {w0, w1, w2, w3, w4, w5, w6};
    int idx = blockIdx.x * 256 + threadIdx.x;
    if (idx >= SZ[li]) return;
    const float* W = Ws[li];
    float v = 0.f;
    if (li == 0) {
        int f = idx & 31;
        if (f < 15) { int o = idx >> 5; int k = f / 3, c = f % 3; v = W[o * 15 + c * 5 + k]; }
    } else {
        int Ci = CI[li], nch = NCHt[li];
        int rl = nch * 160;
        int o = idx / rl, r = idx - o * rl;
        int ch = r / 160, kk = r - ch * 160;
        int d = kk >> 5, c = ch * 32 + (kk & 31);
        v = W[(size_t)o * 5 * Ci + c * 5 + d];
    }
    Wb[OFF[li] + idx] = __float2bfloat16(v);
}

// ---------------------------------------------------------------------------
// Layer 0 Chebyshev expansion: Ci=3, KdPad=32, input [B, 3, V] -> F0 [M,32] bf16.
__global__ __launch_bounds__(512, 4)
void k_cheb0(const float* __restrict__ X, __hip_bfloat16* __restrict__ F) {
    __shared__ float T[3][3072];
    int tid = threadIdx.x;
    int b = blockIdx.x;
    size_t fBase = ((size_t)b) << 10;
    for (int i = tid; i < 3072; i += 512) {
        int u = i / 3, c = i - (i / 3) * 3;
        float v = X[((size_t)b * 3 + c) * GV + u];
        F[(fBase + u) * 32 + c] = __float2bfloat16(v);
        int gi = u >> 5, gj = u & 31;
        int deg = (gi > 0) + (gi < 31) + (gj > 0) + (gj < 31);
        T[0][i] = v * rsqrtf((float)deg);
    }
    for (int i = tid; i < 1024 * 17; i += 512) {
        int u = i / 17, f = i - (i / 17) * 17;
        F[(fBase + u) * 32 + 15 + f] = __float2bfloat16(0.f);
    }
    __syncthreads();
    for (int k = 1; k < CHEB_K; ++k) {
        const float* src = T[(k - 1) % 3];
        const float* old = T[(k + 1) % 3];
        float* dst = T[k % 3];
        for (int i = tid; i < 3072; i += 512) {
            int u = i / 3, c = i - (i / 3) * 3;
            int gi = u >> 5, gj = u & 31;
            float s = 0.f;
            if (gi > 0)  s += src[i - 96];
            if (gi < 31) s += src[i + 96];
            if (gj > 0)  s += src[i - 3];
            if (gj < 31) s += src[i + 3];
            int deg = (gi > 0) + (gi < 31) + (gj > 0) + (gj < 31);
            float invdeg = (deg == 4) ? 0.25f : (deg == 3 ? (1.f / 3.f) : 0.5f);
            float val = (k == 1) ? (-s * invdeg) : (-2.f * invdeg * s - old[i]);
            dst[i] = val;
            F[(fBase + u) * 32 + k * 3 + c] = __float2bfloat16(val * sqrtf((float)deg));
        }
        __syncthreads();
    }
}

// ---------------------------------------------------------------------------
// Layer 0 GEMM: Y[b][96][v] = F0[M,32] @ Wb0[96,32]^T, + stats for BN1.
__global__ __launch_bounds__(256, 2)
void k_gemm_l0(const __hip_bfloat16* __restrict__ A, const __hip_bfloat16* __restrict__ Bw,
               float* __restrict__ Y, float* __restrict__ stats) {
    __shared__ float ls[192];
    int tid = threadIdx.x;
    for (int t = tid; t < 192; t += 256) ls[t] = 0.f;
    __syncthreads();
    int lane = tid & 63, wv = tid >> 6;
    int col = lane & 15, quad = lane >> 4;
    size_t m0 = (size_t)blockIdx.x * 128 + wv * 32;
    f32x4 acc[2][6];
    #pragma unroll
    for (int t = 0; t < 2; ++t)
        #pragma unroll
        for (int n = 0; n < 6; ++n) acc[t][n] = (f32x4){0.f, 0.f, 0.f, 0.f};
    bf16x8 a0 = *(const bf16x8*)(A + (m0 + col) * 32 + quad * 8);
    bf16x8 a1 = *(const bf16x8*)(A + (m0 + 16 + col) * 32 + quad * 8);
    #pragma unroll
    for (int n = 0; n < 6; ++n) {
        bf16x8 bf = *(const bf16x8*)(Bw + (size_t)(n * 16 + col) * 32 + quad * 8);
        acc[0][n] = __builtin_amdgcn_mfma_f32_16x16x32_bf16(a0, bf, acc[0][n], 0, 0, 0);
        acc[1][n] = __builtin_amdgcn_mfma_f32_16x16x32_bf16(a1, bf, acc[1][n], 0, 0, 0);
    }
    int b = (int)(m0 >> 10);
    int v0 = (int)(m0 & 1023);
    #pragma unroll
    for (int t = 0; t < 2; ++t) {
        #pragma unroll
        for (int n = 0; n < 6; ++n) {
            int cg = n * 16 + col;
            int vv = v0 + t * 16 + quad * 4;
            f32x4 val = acc[t][n];
            *(f32x4*)(Y + ((size_t)b * 96 + cg) * 1024 + vv) = val;
            float s1 = val[0] + val[1] + val[2] + val[3];
            float s2 = val[0]*val[0] + val[1]*val[1] + val[2]*val[2] + val[3]*val[3];
            s1 += __shfl_xor(s1, 16, 64); s1 += __shfl_xor(s1, 32, 64);
            s2 += __shfl_xor(s2, 16, 64); s2 += __shfl_xor(s2, 32, 64);
            if (quad == 0) { atomicAdd(&ls[cg], s1); atomicAdd(&ls[96 + cg], s2); }
        }
    }
    __syncthreads();
    for (int t = tid; t < 192; t += 256) atomicAdd(&stats[t], ls[t]);
}

// ---------------------------------------------------------------------------
// FUSED layer (layers 1..6): BN+ReLU(prev) -> Chebyshev stencil in LDS (halo
// recursion, degree-scaled space) -> MFMA GEMM vs Wt -> Y [B][CO][V] + stats.
// Block: 256 output nodes (8 grid-rows) of one batch elem; stages 16 grid-rows
// (4-row halo each side). K streamed in 32-channel chunks; per chunk 5 phases,
// each = {B-frag loads, stencil producing next degree, MFMA of current degree}.
// Two rotating fp32 S-buffers (in-place S_k = f(S_{k-1}) - S_{k-2}).
// LDS swizzle: float addr = ln*32 + ((cgrp ^ (ln&7))<<2)  (2-way max).
template<int CIN, int NT>
__global__ __launch_bounds__(512, 2)
void k_fused(const float* __restrict__ X, const float* __restrict__ pstats,
             const float* __restrict__ g, const float* __restrict__ bb,
             const __hip_bfloat16* __restrict__ Wt,
             float* __restrict__ Y, float* __restrict__ stats) {
    constexpr int CO = NT * 16;
    constexpr int NCH = CIN / 32;
    __shared__ __align__(16) float Sb0[512 * 32];
    __shared__ __align__(16) float Sb1[512 * 32];
    __shared__ __align__(16) float risq[512];
    __shared__ float sdeg[512];
    __shared__ float ls[2 * CO];
    int tid = threadIdx.x;
    int b = blockIdx.y;
    int n0 = blockIdx.x * 256 - 128;          // staged-node 0 -> global node n0
    int j = tid & 127, kg = tid >> 7;          // stencil/stage mapping
    int lane = tid & 63, wv = tid >> 6;
    int col = lane & 15, quad = lane >> 4;
    const float invM = 1.0f / (float)M_TOT;

    {   // per-block tables (staged-local node -> rsqrt(deg), sqrt(deg))
        int u = tid;
        if (u < 512) {
            int gn = n0 + u;
            int gi = gn >> 5, gj = gn & 31;
            int deg = (gi > 0) + (gi < 31) + (gj > 0) + (gj < 31);
            float fd = (float)deg;
            risq[u] = rsqrtf(fd);
            sdeg[u] = sqrtf(fd);
        }
    }
    for (int t = tid; t < 2 * CO; t += 512) ls[t] = 0.f;

    f32x4 acc[2][NT];
    #pragma unroll
    for (int t = 0; t < 2; ++t)
        #pragma unroll
        for (int n = 0; n < NT; ++n) acc[t][n] = (f32x4){0.f, 0.f, 0.f, 0.f};

    // phase: MFMA degree d (A from SA) + stencil producing degree d+1 into SD.
    // mode: 0 = first stencil (S1), 1 = general stencil, 2 = no stencil.
    auto phase = [&](int ch, int d, const float* SA, float* SD, int mode) {
        bf16x8 bfr[NT];
        const __hip_bfloat16* Bp = Wt + (size_t)col * (NCH * 160) + ch * 160 + d * 32 + quad * 8;
        #pragma unroll
        for (int n = 0; n < NT; ++n)
            bfr[n] = *(const bf16x8*)(Bp + (size_t)(n * 16) * (NCH * 160));
        if (mode < 2) {
            #pragma unroll
            for (int i = 0; i < 4; ++i) {
                int ln = j + 128 * i;
                int gn = n0 + ln;
                int gi = gn >> 5, gj = gn & 31;
                float iv = risq[ln] * risq[ln];          // 1/deg
                int s7 = ln & 7;
                int upo = (ln >= 32)  ? -1024 : 0;       // clamped (halo garbage ok)
                int dno = (ln < 480)  ?  1024 : 0;
                #pragma unroll
                for (int cgi = 0; cgi < 2; ++cgi) {
                    int cg = 2 * kg + cgi;
                    int own = (ln << 5) + ((cg ^ s7) << 2);
                    f32x4 s4 = (f32x4){0.f, 0.f, 0.f, 0.f};
                    if (gi > 0)  s4 += *(const f32x4*)(SA + own + upo);
                    if (gi < 31) s4 += *(const f32x4*)(SA + own + dno);
                    if (gj > 0)  s4 += *(const f32x4*)(SA + ((ln - 1) << 5) + ((cg ^ ((ln - 1) & 7)) << 2));
                    if (gj < 31) s4 += *(const f32x4*)(SA + ((ln + 1) << 5) + ((cg ^ ((ln + 1) & 7)) << 2));
                    f32x4 val;
                    if (mode == 0) val = s4 * (-iv);
                    else           val = s4 * (-2.f * iv) - *(const f32x4*)(SD + own);
                    *(f32x4*)(SD + own) = val;
                }
            }
        }
        // A fragments (16 nodes each, *sqrt(deg), cvt bf16) + MFMA
        bf16x8 afr[2];
        #pragma unroll
        for (int t = 0; t < 2; ++t) {
            int node = 128 + ((2 * wv + t) << 4) + col;
            int s7 = node & 7;
            int g0 = 2 * quad;
            f32x4 lo = *(const f32x4*)(SA + (node << 5) + ((g0 ^ s7) << 2));
            f32x4 hi = *(const f32x4*)(SA + (node << 5) + (((g0 + 1) ^ s7) << 2));
            float sd = sdeg[node];
            union { __hip_bfloat16 h[8]; bf16x8 v; } u;
            #pragma unroll
            for (int e = 0; e < 4; ++e) {
                u.h[e]     = __float2bfloat16(lo[e] * sd);
                u.h[4 + e] = __float2bfloat16(hi[e] * sd);
            }
            afr[t] = u.v;
        }
        #pragma unroll
        for (int n = 0; n < NT; ++n) {
            acc[0][n] = __builtin_amdgcn_mfma_f32_16x16x32_bf16(afr[0], bfr[n], acc[0][n], 0, 0, 0);
            acc[1][n] = __builtin_amdgcn_mfma_f32_16x16x32_bf16(afr[1], bfr[n], acc[1][n], 0, 0, 0);
        }
    };

    for (int ch = 0; ch < NCH; ++ch) {
        __syncthreads();   // Sb0 free (prev chunk's mma(4) done); 1st iter: tables ready
        {   // ---- stage S0 (BN+ReLU+rsqrt(deg)) into Sb0 ----
            const float* Xc = X + ((size_t)b * CIN + ch * 32) * 1024;
            int gn0 = n0 + 4 * j;
            bool inb = (gn0 >= 0) && (gn0 < 1024);
            f32x4 r4 = *(const f32x4*)(risq + 4 * j);
            f32x4 vv[8];
            #pragma unroll
            for (int e = 0; e < 8; ++e) {
                int cglob = ch * 32 + 8 * kg + e;
                float mn = pstats[cglob] * invM;
                float vr = pstats[CIN + cglob] * invM - mn * mn;
                float sc = rsqrtf(vr + 1e-5f) * g[cglob];
                float of = bb[cglob] - mn * sc;
                f32x4 v = (f32x4){0.f, 0.f, 0.f, 0.f};
                if (inb) v = *(const f32x4*)(Xc + (size_t)(8 * kg + e) * 1024 + gn0);
                #pragma unroll
                for (int q2 = 0; q2 < 4; ++q2) {
                    float xx = v[q2] * sc + of;
                    xx = xx > 0.f ? xx : 0.f;
                    v[q2] = xx * r4[q2];
                }
                vv[e] = v;
            }
            #pragma unroll
            for (int i2 = 0; i2 < 4; ++i2) {
                int ln = 4 * j + i2;
                int s7 = ln & 7;
                f32x4 w0 = (f32x4){vv[0][i2], vv[1][i2], vv[2][i2], vv[3][i2]};
                f32x4 w1 = (f32x4){vv[4][i2], vv[5][i2], vv[6][i2], vv[7][i2]};
                *(f32x4*)(Sb0 + (ln << 5) + (((2 * kg)     ^ s7) << 2)) = w0;
                *(f32x4*)(Sb0 + (ln << 5) + (((2 * kg + 1) ^ s7) << 2)) = w1;
            }
        }
        __syncthreads();
        phase(ch, 0, Sb0, Sb1, 0);   // mma S0, stencil -> S1
        __syncthreads();
        phase(ch, 1, Sb1, Sb0, 1);   // mma S1, stencil -> S2 (over S0)
        __syncthreads();
        phase(ch, 2, Sb0, Sb1, 1);   // mma S2, stencil -> S3 (over S1)
        __syncthreads();
        phase(ch, 3, Sb1, Sb0, 1);   // mma S3, stencil -> S4 (over S2)
        __syncthreads();
        phase(ch, 4, Sb0, nullptr, 2); // mma S4
    }

    // ---- epilogue: Y store (16B) + per-channel stats ----
    int gnb = blockIdx.x * 256;
    #pragma unroll
    for (int t = 0; t < 2; ++t) {
        int gn0 = gnb + ((2 * wv + t) << 4) + quad * 4;
        #pragma unroll
        for (int n = 0; n < NT; ++n) {
            int cg = n * 16 + col;
            f32x4 val = acc[t][n];
            *(f32x4*)(Y + ((size_t)b * CO + cg) * 1024 + gn0) = val;
            float s1 = val[0] + val[1] + val[2] + val[3];
            float s2 = val[0]*val[0] + val[1]*val[1] + val[2]*val[2] + val[3]*val[3];
            s1 += __shfl_xor(s1, 16, 64); s1 += __shfl_xor(s1, 32, 64);
            s2 += __shfl_xor(s2, 16, 64); s2 += __shfl_xor(s2, 32, 64);
            if (quad == 0) { atomicAdd(&ls[cg], s1); atomicAdd(&ls[CO + cg], s2); }
        }
    }
    __syncthreads();
    for (int t = tid; t < 2 * CO; t += 512) atomicAdd(&stats[t], ls[t]);
}

// ---------------------------------------------------------------------------
// Classifier with fused final BN+ReLU: h [B][96][V] fp32 (pre-BN).
__global__ void k_classifier(const float* __restrict__ h, const float* __restrict__ stats,
                             const float* __restrict__ g, const float* __restrict__ bb,
                             const float* __restrict__ w, const float* __restrict__ bias,
                             float* __restrict__ out) {
    int b = blockIdx.x, o = blockIdx.y;
    const float4* hb = (const float4*)(h + (size_t)b * 96 * GV);
    const float4* wo = (const float4*)(w + (size_t)o * 96 * GV);
    const float invM = 1.0f / (float)M_TOT;
    float acc = 0.f;
    for (int f = threadIdx.x; f < 96 * GV / 4; f += 256) {
        int c = f >> 8;
        float mn = stats[c] * invM;
        float vr = stats[96 + c] * invM - mn * mn;
        float sc = rsqrtf(vr + 1e-5f) * g[c];
        float of = bb[c] - mn * sc;
        float4 a = hb[f], c4 = wo[f];
        float x0 = fmaxf(a.x * sc + of, 0.f);
        float x1 = fmaxf(a.y * sc + of, 0.f);
        float x2 = fmaxf(a.z * sc + of, 0.f);
        float x3 = fmaxf(a.w * sc + of, 0.f);
        acc += x0 * c4.x + x1 * c4.y + x2 * c4.z + x3 * c4.w;
    }
    #pragma unroll
    for (int off = 32; off > 0; off >>= 1) acc += __shfl_down(acc, off, 64);
    __shared__ float red[4];
    int lane = threadIdx.x & 63, wvv = threadIdx.x >> 6;
    if (lane == 0) red[wvv] = acc;
    __syncthreads();
    if (threadIdx.x == 0) out[b * 10 + o] = red[0] + red[1] + red[2] + red[3] + bias[o];
}

// ---------------------------------------------------------------------------
extern "C" void kernel_launch(void* const* d_in, const int* in_sizes, int n_in,
                              void* d_out, int out_size, void* d_ws, size_t ws_size,
                              hipStream_t stream) {
    const float* x = (const float*)d_in[0];
    const float* wts[7]; const float* gs[7]; const float* bs[7];
    for (int i = 0; i < 7; ++i) {
        wts[i] = (const float*)d_in[2 + 3 * i];
        gs[i]  = (const float*)d_in[3 + 3 * i];
        bs[i]  = (const float*)d_in[4 + 3 * i];
    }
    const float* clfw = (const float*)d_in[23];
    const float* clfb = (const float*)d_in[24];
    float* out = (float*)d_out;

    // ---- workspace layout (floats) ----
    const size_t BIG = (size_t)M_TOT * 192;
    float* ws = (float*)d_ws;
    float* bufA = ws;
    float* bufB = ws + BIG;
    float* stats = ws + 2 * BIG;                        // 7 * 384 floats
    __hip_bfloat16* Wb = (__hip_bfloat16*)(stats + 7 * 384);
    __hip_bfloat16* F0 = Wb + WTOT;                     // [M,32] bf16

    hipMemsetAsync(stats, 0, 7 * 384 * sizeof(float), stream);
    hipLaunchKernelGGL(k_convw_all, dim3(720, 7), dim3(256), 0, stream,
                       wts[0], wts[1], wts[2], wts[3], wts[4], wts[5], wts[6], Wb);

    // layer 0
    hipLaunchKernelGGL(k_cheb0, dim3(BATCH), dim3(512), 0, stream, x, F0);
    hipLaunchKernelGGL(k_gemm_l0, dim3(M_TOT / 128), dim3(256), 0, stream,
                       F0, Wb + WOFF0, bufA, stats);

    // fused layers 1..6 (BN of prev layer applied on load)
    // CHANNELS: l1 (96,96) l2 (96,96) l3 (96,192) l4 (192,192) l5 (192,192) l6 (192,96)
    dim3 fg(4, BATCH);
    hipLaunchKernelGGL((k_fused<96, 6>),   fg, dim3(512), 0, stream,
                       bufA, stats + 0 * 384, gs[0], bs[0], Wb + WOFF1, bufB, stats + 1 * 384);
    hipLaunchKernelGGL((k_fused<96, 6>),   fg, dim3(512), 0, stream,
                       bufB, stats + 1 * 384, gs[1], bs[1], Wb + WOFF2, bufA, stats + 2 * 384);
    hipLaunchKernelGGL((k_fused<96, 12>),  fg, dim3(512), 0, stream,
                       bufA, stats + 2 * 384, gs[2], bs[2], Wb + WOFF3, bufB, stats + 3 * 384);
    hipLaunchKernelGGL((k_fused<192, 12>), fg, dim3(512), 0, stream,
                       bufB, stats + 3 * 384, gs[3], bs[3], Wb + WOFF4, bufA, stats + 4 * 384);
    hipLaunchKernelGGL((k_fused<192, 12>), fg, dim3(512), 0, stream,
                       bufA, stats + 4 * 384, gs[4], bs[4], Wb + WOFF5, bufB, stats + 5 * 384);
    hipLaunchKernelGGL((k_fused<192, 6>),  fg, dim3(512), 0, stream,
                       bufB, stats + 5 * 384, gs[5], bs[5], Wb + WOFF6, bufA, stats + 6 * 384);

    // classifier with fused BN6+ReLU
    hipLaunchKernelGGL(k_classifier, dim3(BATCH, 10), dim3(256), 0, stream,
                       bufA, stats + 6 * 384, gs[6], bs[6], clfw, clfb, out);
}